// Round 4
// baseline (1858.601 us; speedup 1.0000x reference)
//
#include <hip/hip_runtime.h>
#include <hip/hip_bf16.h>
#include <math.h>

#define EPS_ 1e-5f
constexpr int B_ = 4, NA = 64, T_ = 128, D_ = 128, H_ = 8, L_ = 3, DFF = 512, E_ = 65536;
constexpr int DH = D_ / H_;        // 16
constexpr int NN = T_ * NA;        // 8192
constexpr int NTOT = B_ * NA * T_; // 32768

// ---------------- embed: x = hist@W + b ; e = x + posenc ----------------
__global__ __launch_bounds__(256) void embed_kernel(
    const float* __restrict__ hist, const float* __restrict__ w,
    const float* __restrict__ b, float* __restrict__ x, float* __restrict__ e) {
  int idx = blockIdx.x * 256 + threadIdx.x;
  if (idx >= NTOT * D_) return;
  int d = idx & (D_ - 1);
  int r = idx >> 7;
  int t = r & (T_ - 1);
  const float* hp = hist + (size_t)r * 3;
  float acc = b[d];
  acc += hp[0] * w[0 * D_ + d];
  acc += hp[1] * w[1 * D_ + d];
  acc += hp[2] * w[2 * D_ + d];
  x[idx] = acc;
  int p = d >> 1;
  float ang = (float)t * expf(-logf(10000.f) * (2.f * (float)p) / (float)D_);
  float pe = (d & 1) ? cosf(ang) : sinf(ang);
  e[idx] = acc + pe;
}

// ---------------- generic fp32 GEMM: C = A[M,K] @ W[K,N] + bias, opt ReLU ----------------
template <int RELU>
__global__ __launch_bounds__(256) void gemm_kernel(
    const float* __restrict__ A, const float* __restrict__ W,
    const float* __restrict__ bias, float* __restrict__ C,
    int M, int N, int K) {
  __shared__ float As[64][17];
  __shared__ float Ws[16][65];
  int tx = threadIdx.x & 15, ty = threadIdx.x >> 4;
  int row0 = blockIdx.y * 64;
  int col0 = blockIdx.x * 64;
  float acc[4][4] = {};
  for (int k0 = 0; k0 < K; k0 += 16) {
    for (int i = threadIdx.x; i < 64 * 16; i += 256) {
      int r = i >> 4, c = i & 15;
      As[r][c] = A[(size_t)(row0 + r) * K + k0 + c];
    }
    for (int i = threadIdx.x; i < 16 * 64; i += 256) {
      int r = i >> 6, c = i & 63;
      Ws[r][c] = W[(size_t)(k0 + r) * N + col0 + c];
    }
    __syncthreads();
#pragma unroll
    for (int kk = 0; kk < 16; ++kk) {
      float a[4], w[4];
#pragma unroll
      for (int i = 0; i < 4; ++i) a[i] = As[ty * 4 + i][kk];
#pragma unroll
      for (int j = 0; j < 4; ++j) w[j] = Ws[kk][tx * 4 + j];
#pragma unroll
      for (int i = 0; i < 4; ++i)
#pragma unroll
        for (int j = 0; j < 4; ++j) acc[i][j] += a[i] * w[j];
    }
    __syncthreads();
  }
#pragma unroll
  for (int j = 0; j < 4; ++j) {
    float bj = bias[col0 + tx * 4 + j];
#pragma unroll
    for (int i = 0; i < 4; ++i) {
      float v = acc[i][j] + bj;
      if (RELU) v = fmaxf(v, 0.f);
      C[(size_t)(row0 + ty * 4 + i) * N + col0 + tx * 4 + j] = v;
    }
  }
}

// ---------------- attention: one block per (b,n,h,row-half) ----------------
__global__ __launch_bounds__(256) void attn_kernel(
    const float* __restrict__ q, const float* __restrict__ k,
    const float* __restrict__ v, float* __restrict__ o) {
  const int half = blockIdx.x & 1;
  const int h = (blockIdx.x >> 1) & (H_ - 1);
  const int bn = blockIdx.x >> 4;
  const float* qb = q + (size_t)bn * T_ * D_ + h * DH;
  const float* kb = k + (size_t)bn * T_ * D_ + h * DH;
  const float* vb = v + (size_t)bn * T_ * D_ + h * DH;
  __shared__ float Qs[64][DH];
  __shared__ float Ks[T_][DH];
  __shared__ float Vs[T_][DH];
  __shared__ float Sc[64][T_ + 1];
  for (int i = threadIdx.x; i < T_ * DH; i += 256) {
    int t = i >> 4, d = i & (DH - 1);
    Ks[t][d] = kb[(size_t)t * D_ + d];
    Vs[t][d] = vb[(size_t)t * D_ + d];
  }
  for (int i = threadIdx.x; i < 64 * DH; i += 256) {
    int t = i >> 4, d = i & (DH - 1);
    Qs[t][d] = qb[(size_t)(half * 64 + t) * D_ + d];
  }
  __syncthreads();
  const float scale = 0.25f; // 1/sqrt(DH), DH=16
  for (int i = threadIdx.x; i < 64 * T_; i += 256) {
    int ti = i >> 7, tj = i & (T_ - 1);
    float s = 0.f;
#pragma unroll
    for (int d = 0; d < DH; ++d) s += Qs[ti][d] * Ks[tj][d];
    Sc[ti][tj] = s * scale;
  }
  __syncthreads();
  if (threadIdx.x < 64) {
    int r = threadIdx.x;
    float m = -1e30f;
    for (int j = 0; j < T_; ++j) m = fmaxf(m, Sc[r][j]);
    float sum = 0.f;
    for (int j = 0; j < T_; ++j) {
      float e = expf(Sc[r][j] - m);
      Sc[r][j] = e;
      sum += e;
    }
    float inv = 1.f / sum;
    for (int j = 0; j < T_; ++j) Sc[r][j] *= inv;
  }
  __syncthreads();
  float* ob = o + (size_t)bn * T_ * D_ + h * DH;
  for (int i = threadIdx.x; i < 64 * DH; i += 256) {
    int t = i >> 4, d = i & (DH - 1);
    float s = 0.f;
    for (int j = 0; j < T_; ++j) s += Sc[t][j] * Vs[j][d];
    ob[(size_t)(half * 64 + t) * D_ + d] = s;
  }
}

// ---------------- residual add + LayerNorm (one 128-thread block per row) ----------------
// In-place safe for out == a or out == b.
__global__ __launch_bounds__(128) void add_ln_kernel(
    const float* __restrict__ a, const float* __restrict__ b,
    const float* __restrict__ gam, const float* __restrict__ bet,
    float* __restrict__ out) {
  int r = blockIdx.x;
  int d = threadIdx.x;
  float val = a[(size_t)r * D_ + d] + b[(size_t)r * D_ + d];
  __shared__ float red[4];
  float s = val;
#pragma unroll
  for (int off = 32; off; off >>= 1) s += __shfl_down(s, off, 64);
  if ((d & 63) == 0) red[d >> 6] = s;
  __syncthreads();
  float mean = (red[0] + red[1]) * (1.f / (float)D_);
  float dv = val - mean;
  float q = dv * dv;
#pragma unroll
  for (int off = 32; off; off >>= 1) q += __shfl_down(q, off, 64);
  if ((d & 63) == 0) red[2 + (d >> 6)] = q;
  __syncthreads();
  float var = (red[2] + red[3]) * (1.f / (float)D_);
  out[(size_t)r * D_ + d] = dv * rsqrtf(var + EPS_) * gam[d] + bet[d];
}

// ---------------- gating dot: s[b, t*NA+n] = <out_e[b,n,t,:], x[b,n,t,:]> ----------------
__global__ __launch_bounds__(256) void sdot_kernel(
    const float* __restrict__ e, const float* __restrict__ x, float* __restrict__ s) {
  int r = blockIdx.x * 4 + (threadIdx.x >> 6);
  int lane = threadIdx.x & 63;
  const float* ep = e + (size_t)r * D_;
  const float* xp = x + (size_t)r * D_;
  float acc = ep[lane] * xp[lane] + ep[lane + 64] * xp[lane + 64];
#pragma unroll
  for (int off = 32; off; off >>= 1) acc += __shfl_down(acc, off, 64);
  if (lane == 0) {
    int t = r & (T_ - 1);
    int bn = r >> 7;
    int n = bn & (NA - 1);
    int b = bn >> 6;
    s[(size_t)b * NN + t * NA + n] = acc;
  }
}

// ---------------- edge scatter: g[b,dst] += ew * s[b,src] ----------------
__global__ __launch_bounds__(256) void scatter_kernel(
    const float* __restrict__ s, const int* __restrict__ ei,
    const float* __restrict__ ew, float* __restrict__ g) {
  int idx = blockIdx.x * 256 + threadIdx.x;
  if (idx >= B_ * E_) return;
  int b = idx >> 16; // E_ = 65536
  int e = idx & (E_ - 1);
  int src = ei[(size_t)b * 2 * E_ + e];
  int dst = ei[(size_t)b * 2 * E_ + E_ + e];
  float w = ew[(size_t)b * E_ + e];
  atomicAdd(&g[(size_t)b * NN + dst], w * s[(size_t)b * NN + src]);
}

// ---------------- global mean / rsqrt(var) over g ----------------
__global__ __launch_bounds__(1024) void stats_kernel(
    const float* __restrict__ g, float* __restrict__ st) {
  float sum = 0.f, sq = 0.f;
  for (int i = threadIdx.x; i < B_ * NN; i += 1024) {
    float v = g[i];
    sum += v;
    sq += v * v;
  }
#pragma unroll
  for (int off = 32; off; off >>= 1) {
    sum += __shfl_down(sum, off, 64);
    sq += __shfl_down(sq, off, 64);
  }
  __shared__ float s1[16], s2[16];
  int w = threadIdx.x >> 6;
  if ((threadIdx.x & 63) == 0) {
    s1[w] = sum;
    s2[w] = sq;
  }
  __syncthreads();
  if (threadIdx.x == 0) {
    float ts = 0.f, tq = 0.f;
    for (int i = 0; i < 16; ++i) {
      ts += s1[i];
      tq += s2[i];
    }
    float n = (float)(B_ * NN);
    float m = ts / n;
    float var = tq / n - m * m;
    st[0] = m;
    st[1] = rsqrtf(var + EPS_);
  }
}

// ---------------- final: out[b,n,t,d] = norm(g[b,t,n]) * lw[d] + lb[d]  (fp32 out) ----------------
__global__ __launch_bounds__(256) void final_kernel(
    const float* __restrict__ g, const float* __restrict__ st,
    const float* __restrict__ bng, const float* __restrict__ bnb,
    const float* __restrict__ lw, const float* __restrict__ lb,
    float* __restrict__ out) {
  int idx = blockIdx.x * 256 + threadIdx.x;
  if (idx >= NTOT * D_) return;
  int d = idx & (D_ - 1);
  int r = idx >> 7;
  int t = r & (T_ - 1);
  int bn = r >> 7;
  int n = bn & (NA - 1);
  int b = bn >> 6;
  float gv = g[(size_t)b * NN + t * NA + n];
  float val = (gv - st[0]) * st[1] * bng[0] + bnb[0];
  out[idx] = val * lw[d] + lb[d];
}

extern "C" void kernel_launch(void* const* d_in, const int* in_sizes, int n_in,
                              void* d_out, int out_size, void* d_ws, size_t ws_size,
                              hipStream_t stream) {
  const float* hist = (const float*)d_in[0];
  const int* eidx = (const int*)d_in[1];
  const float* ew = (const float*)d_in[2];
  const float* hw = (const float*)d_in[3];
  const float* hb = (const float*)d_in[4];
  const float* wq = (const float*)d_in[5];
  const float* bq = (const float*)d_in[6];
  const float* wk = (const float*)d_in[7];
  const float* bk = (const float*)d_in[8];
  const float* wv = (const float*)d_in[9];
  const float* bv = (const float*)d_in[10];
  const float* wo = (const float*)d_in[11];
  const float* bo = (const float*)d_in[12];
  const float* ln1g = (const float*)d_in[13];
  const float* ln1b = (const float*)d_in[14];
  const float* w1 = (const float*)d_in[15];
  const float* b1 = (const float*)d_in[16];
  const float* w2 = (const float*)d_in[17];
  const float* b2 = (const float*)d_in[18];
  const float* ln2g = (const float*)d_in[19];
  const float* ln2b = (const float*)d_in[20];
  const float* bng = (const float*)d_in[21];
  const float* bnb = (const float*)d_in[22];
  const float* lgw = (const float*)d_in[23];
  const float* lgb = (const float*)d_in[24];
  float* out = (float*)d_out;

  // ---- workspace layout: 6 fp32 NE-buffers + scratch = ~101 MB ----
  // A0=bx (live whole pass), A1=be, A2=q/o, A3=k/h1, A4=v, A5=ctx.
  // FF intermediate (NTOT x DFF fp32) runs in TWO row-chunks of 16384;
  // each 32 MB chunk aliases {A4,A5} (dead after O-proj). ff2 -> A1 (dead
  // after LN1); add_ln2(h1, A1) -> A1 is in-place safe.
  float* ws = (float*)d_ws;
  const size_t NE = (size_t)NTOT * D_; // 4,194,304 floats
  float* bx = ws + 0 * NE;
  float* be = ws + 1 * NE;
  float* q_ = ws + 2 * NE;
  float* k_ = ws + 3 * NE; // -> h1
  float* v_ = ws + 4 * NE;
  float* ct = ws + 5 * NE;
  float* bs_ = ws + 6 * NE; // NTOT floats
  float* bg_ = bs_ + NTOT;  // NTOT floats
  float* bst = bg_ + NTOT;  // 2 floats

  embed_kernel<<<(NTOT * D_) / 256, 256, 0, stream>>>(hist, hw, hb, bx, be);

  for (int l = 0; l < L_; ++l) {
    const float* wql = wq + (size_t)l * D_ * D_;
    const float* wkl = wk + (size_t)l * D_ * D_;
    const float* wvl = wv + (size_t)l * D_ * D_;
    const float* wol = wo + (size_t)l * D_ * D_;
    dim3 gDD(D_ / 64, NTOT / 64);
    gemm_kernel<0><<<gDD, 256, 0, stream>>>(be, wql, bq + l * D_, q_, NTOT, D_, D_);
    gemm_kernel<0><<<gDD, 256, 0, stream>>>(be, wkl, bk + l * D_, k_, NTOT, D_, D_);
    gemm_kernel<0><<<gDD, 256, 0, stream>>>(be, wvl, bv + l * D_, v_, NTOT, D_, D_);
    attn_kernel<<<B_ * NA * H_ * 2, 256, 0, stream>>>(q_, k_, v_, ct);
    gemm_kernel<0><<<gDD, 256, 0, stream>>>(ct, wol, bo + l * D_, q_, NTOT, D_, D_);
    add_ln_kernel<<<NTOT, 128, 0, stream>>>(be, q_, ln1g + l * D_, ln1b + l * D_, k_);
    for (int c = 0; c < 2; ++c) {
      const int r0 = c * (NTOT / 2);
      gemm_kernel<1><<<dim3(DFF / 64, (NTOT / 2) / 64), 256, 0, stream>>>(
          k_ + (size_t)r0 * D_, w1 + (size_t)l * D_ * DFF, b1 + l * DFF, v_,
          NTOT / 2, DFF, D_);
      gemm_kernel<0><<<dim3(D_ / 64, (NTOT / 2) / 64), 256, 0, stream>>>(
          v_, w2 + (size_t)l * DFF * D_, b2 + l * D_, be + (size_t)r0 * D_,
          NTOT / 2, D_, DFF);
    }
    add_ln_kernel<<<NTOT, 128, 0, stream>>>(k_, be, ln2g + l * D_, ln2b + l * D_, be);
  }

  sdot_kernel<<<NTOT / 4, 256, 0, stream>>>(be, bx, bs_);
  hipMemsetAsync(bg_, 0, (size_t)B_ * NN * sizeof(float), stream);
  scatter_kernel<<<(B_ * E_) / 256, 256, 0, stream>>>(bs_, eidx, ew, bg_);
  stats_kernel<<<1, 1024, 0, stream>>>(bg_, bst);
  final_kernel<<<(NTOT * D_) / 256, 256, 0, stream>>>(bg_, bst, bng, bnb, lgw, lgb, out);
}

// Round 5
// 1081.658 us; speedup vs baseline: 1.7183x; 1.7183x over previous
//
#include <hip/hip_runtime.h>
#include <hip/hip_bf16.h>
#include <math.h>

#define EPS_ 1e-5f
constexpr int B_ = 4, NA = 64, T_ = 128, D_ = 128, H_ = 8, L_ = 3, DFF = 512, E_ = 65536;
constexpr int DH = D_ / H_;        // 16
constexpr int NN = T_ * NA;        // 8192
constexpr int NTOT = B_ * NA * T_; // 32768

typedef __bf16 bf16x8 __attribute__((ext_vector_type(8)));
typedef float f32x4 __attribute__((ext_vector_type(4)));

// ---------------- embed: x = hist@W + b ; e = x + posenc ----------------
__global__ __launch_bounds__(256) void embed_kernel(
    const float* __restrict__ hist, const float* __restrict__ w,
    const float* __restrict__ b, float* __restrict__ x, float* __restrict__ e) {
  int idx = blockIdx.x * 256 + threadIdx.x;
  if (idx >= NTOT * D_) return;
  int d = idx & (D_ - 1);
  int r = idx >> 7;
  int t = r & (T_ - 1);
  const float* hp = hist + (size_t)r * 3;
  float acc = b[d];
  acc += hp[0] * w[0 * D_ + d];
  acc += hp[1] * w[1 * D_ + d];
  acc += hp[2] * w[2 * D_ + d];
  x[idx] = acc;
  int p = d >> 1;
  float ang = (float)t * expf(-logf(10000.f) * (2.f * (float)p) / (float)D_);
  float pe = (d & 1) ? cosf(ang) : sinf(ang);
  e[idx] = acc + pe;
}

// ---------------- weight split+transpose: W[K][N] fp32 -> Wt hi/lo [N][K] bf16 ----------------
// Per-layer layout (elems): q@0, k@16384, v@32768, o@49152, w1t@65536 ([512][128]),
// w2t@131072 ([128][512]); LW = 196608 elems per layer.
__global__ __launch_bounds__(256) void convert_weights(
    const float* __restrict__ wq, const float* __restrict__ wk,
    const float* __restrict__ wv, const float* __restrict__ wo,
    const float* __restrict__ w1, const float* __restrict__ w2,
    __bf16* __restrict__ hi, __bf16* __restrict__ lo) {
  const int LW = 196608;
  int idx = blockIdx.x * 256 + threadIdx.x;
  if (idx >= L_ * LW) return;
  int l = idx / LW;
  int rem = idx - l * LW;
  float src;
  int dst;
  if (rem < 65536) {
    int which = rem >> 14;          // 0..3 : q,k,v,o
    int r2 = rem & 16383;
    int n = r2 >> 7, k = r2 & 127;  // n in [0,128), k in [0,128)
    const float* W = (which == 0) ? wq : (which == 1) ? wk : (which == 2) ? wv : wo;
    src = W[(size_t)l * 16384 + k * 128 + n];
    dst = l * LW + which * 16384 + n * 128 + k;
  } else if (rem < 131072) {
    int r2 = rem - 65536;
    int n = r2 >> 7, k = r2 & 127;  // n in [0,512), k in [0,128)
    src = w1[(size_t)l * 65536 + k * 512 + n];
    dst = l * LW + 65536 + n * 128 + k;
  } else {
    int r2 = rem - 131072;
    int n = r2 >> 9, k = r2 & 511;  // n in [0,128), k in [0,512)
    src = w2[(size_t)l * 65536 + k * 128 + n];
    dst = l * LW + 131072 + n * 512 + k;
  }
  __bf16 h = (__bf16)src;
  hi[dst] = h;
  lo[dst] = (__bf16)(src - (float)h);
}

// ---------------- MFMA GEMM: C = A[M,K](fp32) @ Wt^T + bias, Wt=[N][K] bf16 hi/lo ----------------
// fp32-grade accuracy via A=Ahi+Alo split in-kernel; C += Ahi*Whi + Ahi*Wlo + Alo*Whi.
// Block: 256 thr = 4 waves; block tile 128(M)x64(N); wave tile 32x64.
// Frag layouts (HW-verified, learn_hip m89/m91/m120): A[m=lane&15][k=quad*8+j],
// B^T same shape (n=lane&15), D: col=lane&15, row=quad*4+reg.
template <int RELU>
__global__ __launch_bounds__(256) void gemm_mfma(
    const float* __restrict__ A, const __bf16* __restrict__ Whi,
    const __bf16* __restrict__ Wlo, const float* __restrict__ bias,
    float* __restrict__ C, int M, int N, int K) {
  const int wave = threadIdx.x >> 6;
  const int lane = threadIdx.x & 63;
  const int m16 = lane & 15;
  const int quad = lane >> 4;
  const int row0 = blockIdx.y * 128 + wave * 32;
  const int col0 = blockIdx.x * 64;

  f32x4 acc[2][4] = {};
  for (int k0 = 0; k0 < K; k0 += 32) {
    bf16x8 ahi[2], alo[2];
#pragma unroll
    for (int mf = 0; mf < 2; ++mf) {
      const float* ap = A + (size_t)(row0 + mf * 16 + m16) * K + k0 + quad * 8;
      float4 x0 = *(const float4*)ap;
      float4 x1 = *(const float4*)(ap + 4);
      float xv[8] = {x0.x, x0.y, x0.z, x0.w, x1.x, x1.y, x1.z, x1.w};
#pragma unroll
      for (int j = 0; j < 8; ++j) {
        __bf16 h = (__bf16)xv[j];
        ahi[mf][j] = h;
        alo[mf][j] = (__bf16)(xv[j] - (float)h);
      }
    }
    bf16x8 bhi[4], blo[4];
#pragma unroll
    for (int nf = 0; nf < 4; ++nf) {
      size_t off = (size_t)(col0 + nf * 16 + m16) * K + k0 + quad * 8;
      bhi[nf] = *(const bf16x8*)(Whi + off);
      blo[nf] = *(const bf16x8*)(Wlo + off);
    }
#pragma unroll
    for (int mf = 0; mf < 2; ++mf)
#pragma unroll
      for (int nf = 0; nf < 4; ++nf) {
        acc[mf][nf] = __builtin_amdgcn_mfma_f32_16x16x32_bf16(
            ahi[mf], bhi[nf], acc[mf][nf], 0, 0, 0);
        acc[mf][nf] = __builtin_amdgcn_mfma_f32_16x16x32_bf16(
            ahi[mf], blo[nf], acc[mf][nf], 0, 0, 0);
        acc[mf][nf] = __builtin_amdgcn_mfma_f32_16x16x32_bf16(
            alo[mf], bhi[nf], acc[mf][nf], 0, 0, 0);
      }
  }
#pragma unroll
  for (int mf = 0; mf < 2; ++mf)
#pragma unroll
    for (int nf = 0; nf < 4; ++nf) {
      int c = col0 + nf * 16 + m16;
      float bj = bias[c];
#pragma unroll
      for (int reg = 0; reg < 4; ++reg) {
        int r = row0 + mf * 16 + quad * 4 + reg;
        float v = acc[mf][nf][reg] + bj;
        if (RELU) v = fmaxf(v, 0.f);
        C[(size_t)r * N + c] = v;
      }
    }
}

// ---------------- attention: one block per (b,n,h,row-half) ----------------
__global__ __launch_bounds__(256) void attn_kernel(
    const float* __restrict__ q, const float* __restrict__ k,
    const float* __restrict__ v, float* __restrict__ o) {
  const int half = blockIdx.x & 1;
  const int h = (blockIdx.x >> 1) & (H_ - 1);
  const int bn = blockIdx.x >> 4;
  const float* qb = q + (size_t)bn * T_ * D_ + h * DH;
  const float* kb = k + (size_t)bn * T_ * D_ + h * DH;
  const float* vb = v + (size_t)bn * T_ * D_ + h * DH;
  __shared__ float Qs[64][DH];
  __shared__ float Ks[T_][DH];
  __shared__ float Vs[T_][DH];
  __shared__ float Sc[64][T_ + 1];
  for (int i = threadIdx.x; i < T_ * DH; i += 256) {
    int t = i >> 4, d = i & (DH - 1);
    Ks[t][d] = kb[(size_t)t * D_ + d];
    Vs[t][d] = vb[(size_t)t * D_ + d];
  }
  for (int i = threadIdx.x; i < 64 * DH; i += 256) {
    int t = i >> 4, d = i & (DH - 1);
    Qs[t][d] = qb[(size_t)(half * 64 + t) * D_ + d];
  }
  __syncthreads();
  const float scale = 0.25f; // 1/sqrt(DH), DH=16
  for (int i = threadIdx.x; i < 64 * T_; i += 256) {
    int ti = i >> 7, tj = i & (T_ - 1);
    float s = 0.f;
#pragma unroll
    for (int d = 0; d < DH; ++d) s += Qs[ti][d] * Ks[tj][d];
    Sc[ti][tj] = s * scale;
  }
  __syncthreads();
  if (threadIdx.x < 64) {
    int r = threadIdx.x;
    float m = -1e30f;
    for (int j = 0; j < T_; ++j) m = fmaxf(m, Sc[r][j]);
    float sum = 0.f;
    for (int j = 0; j < T_; ++j) {
      float e = expf(Sc[r][j] - m);
      Sc[r][j] = e;
      sum += e;
    }
    float inv = 1.f / sum;
    for (int j = 0; j < T_; ++j) Sc[r][j] *= inv;
  }
  __syncthreads();
  float* ob = o + (size_t)bn * T_ * D_ + h * DH;
  for (int i = threadIdx.x; i < 64 * DH; i += 256) {
    int t = i >> 4, d = i & (DH - 1);
    float s = 0.f;
    for (int j = 0; j < T_; ++j) s += Sc[t][j] * Vs[j][d];
    ob[(size_t)(half * 64 + t) * D_ + d] = s;
  }
}

// ---------------- residual add + LayerNorm (one 128-thread block per row) ----------------
__global__ __launch_bounds__(128) void add_ln_kernel(
    const float* __restrict__ a, const float* __restrict__ b,
    const float* __restrict__ gam, const float* __restrict__ bet,
    float* __restrict__ out) {
  int r = blockIdx.x;
  int d = threadIdx.x;
  float val = a[(size_t)r * D_ + d] + b[(size_t)r * D_ + d];
  __shared__ float red[4];
  float s = val;
#pragma unroll
  for (int off = 32; off; off >>= 1) s += __shfl_down(s, off, 64);
  if ((d & 63) == 0) red[d >> 6] = s;
  __syncthreads();
  float mean = (red[0] + red[1]) * (1.f / (float)D_);
  float dv = val - mean;
  float q = dv * dv;
#pragma unroll
  for (int off = 32; off; off >>= 1) q += __shfl_down(q, off, 64);
  if ((d & 63) == 0) red[2 + (d >> 6)] = q;
  __syncthreads();
  float var = (red[2] + red[3]) * (1.f / (float)D_);
  out[(size_t)r * D_ + d] = dv * rsqrtf(var + EPS_) * gam[d] + bet[d];
}

// ---------------- gating dot ----------------
__global__ __launch_bounds__(256) void sdot_kernel(
    const float* __restrict__ e, const float* __restrict__ x, float* __restrict__ s) {
  int r = blockIdx.x * 4 + (threadIdx.x >> 6);
  int lane = threadIdx.x & 63;
  const float* ep = e + (size_t)r * D_;
  const float* xp = x + (size_t)r * D_;
  float acc = ep[lane] * xp[lane] + ep[lane + 64] * xp[lane + 64];
#pragma unroll
  for (int off = 32; off; off >>= 1) acc += __shfl_down(acc, off, 64);
  if (lane == 0) {
    int t = r & (T_ - 1);
    int bn = r >> 7;
    int n = bn & (NA - 1);
    int b = bn >> 6;
    s[(size_t)b * NN + t * NA + n] = acc;
  }
}

// ---------------- edge scatter ----------------
__global__ __launch_bounds__(256) void scatter_kernel(
    const float* __restrict__ s, const int* __restrict__ ei,
    const float* __restrict__ ew, float* __restrict__ g) {
  int idx = blockIdx.x * 256 + threadIdx.x;
  if (idx >= B_ * E_) return;
  int b = idx >> 16;
  int e = idx & (E_ - 1);
  int src = ei[(size_t)b * 2 * E_ + e];
  int dst = ei[(size_t)b * 2 * E_ + E_ + e];
  float w = ew[(size_t)b * E_ + e];
  atomicAdd(&g[(size_t)b * NN + dst], w * s[(size_t)b * NN + src]);
}

// ---------------- global mean / rsqrt(var) ----------------
__global__ __launch_bounds__(1024) void stats_kernel(
    const float* __restrict__ g, float* __restrict__ st) {
  float sum = 0.f, sq = 0.f;
  for (int i = threadIdx.x; i < B_ * NN; i += 1024) {
    float v = g[i];
    sum += v;
    sq += v * v;
  }
#pragma unroll
  for (int off = 32; off; off >>= 1) {
    sum += __shfl_down(sum, off, 64);
    sq += __shfl_down(sq, off, 64);
  }
  __shared__ float s1[16], s2[16];
  int w = threadIdx.x >> 6;
  if ((threadIdx.x & 63) == 0) {
    s1[w] = sum;
    s2[w] = sq;
  }
  __syncthreads();
  if (threadIdx.x == 0) {
    float ts = 0.f, tq = 0.f;
    for (int i = 0; i < 16; ++i) {
      ts += s1[i];
      tq += s2[i];
    }
    float n = (float)(B_ * NN);
    float m = ts / n;
    float var = tq / n - m * m;
    st[0] = m;
    st[1] = rsqrtf(var + EPS_);
  }
}

// ---------------- final (fp32 out) ----------------
__global__ __launch_bounds__(256) void final_kernel(
    const float* __restrict__ g, const float* __restrict__ st,
    const float* __restrict__ bng, const float* __restrict__ bnb,
    const float* __restrict__ lw, const float* __restrict__ lb,
    float* __restrict__ out) {
  int idx = blockIdx.x * 256 + threadIdx.x;
  if (idx >= NTOT * D_) return;
  int d = idx & (D_ - 1);
  int r = idx >> 7;
  int t = r & (T_ - 1);
  int bn = r >> 7;
  int n = bn & (NA - 1);
  int b = bn >> 6;
  float gv = g[(size_t)b * NN + t * NA + n];
  float val = (gv - st[0]) * st[1] * bng[0] + bnb[0];
  out[idx] = val * lw[d] + lb[d];
}

extern "C" void kernel_launch(void* const* d_in, const int* in_sizes, int n_in,
                              void* d_out, int out_size, void* d_ws, size_t ws_size,
                              hipStream_t stream) {
  const float* hist = (const float*)d_in[0];
  const int* eidx = (const int*)d_in[1];
  const float* ew = (const float*)d_in[2];
  const float* hw = (const float*)d_in[3];
  const float* hb = (const float*)d_in[4];
  const float* wq = (const float*)d_in[5];
  const float* bq = (const float*)d_in[6];
  const float* wk = (const float*)d_in[7];
  const float* bk = (const float*)d_in[8];
  const float* wv = (const float*)d_in[9];
  const float* bv = (const float*)d_in[10];
  const float* wo = (const float*)d_in[11];
  const float* bo = (const float*)d_in[12];
  const float* ln1g = (const float*)d_in[13];
  const float* ln1b = (const float*)d_in[14];
  const float* w1 = (const float*)d_in[15];
  const float* b1 = (const float*)d_in[16];
  const float* w2 = (const float*)d_in[17];
  const float* b2 = (const float*)d_in[18];
  const float* ln2g = (const float*)d_in[19];
  const float* ln2b = (const float*)d_in[20];
  const float* bng = (const float*)d_in[21];
  const float* bnb = (const float*)d_in[22];
  const float* lgw = (const float*)d_in[23];
  const float* lgb = (const float*)d_in[24];
  float* out = (float*)d_out;

  // ---- workspace: round-4 proven layout + 2.4 MB split weights ----
  float* ws = (float*)d_ws;
  const size_t NE = (size_t)NTOT * D_;
  float* bx = ws + 0 * NE;
  float* be = ws + 1 * NE;
  float* q_ = ws + 2 * NE;
  float* k_ = ws + 3 * NE; // -> h1
  float* v_ = ws + 4 * NE;
  float* ct = ws + 5 * NE; // attn ctx; {v_, ct} doubles as FF-mid chunk
  float* bs_ = ws + 6 * NE;
  float* bg_ = bs_ + NTOT;
  float* bst = bg_ + NTOT;
  const int LW = 196608; // per-layer split-weight elems
  __bf16* whiB = (__bf16*)(bst + 2);
  __bf16* wloB = whiB + (size_t)L_ * LW;

  convert_weights<<<(L_ * LW + 255) / 256, 256, 0, stream>>>(
      wq, wk, wv, wo, w1, w2, whiB, wloB);
  embed_kernel<<<(NTOT * D_) / 256, 256, 0, stream>>>(hist, hw, hb, bx, be);

  for (int l = 0; l < L_; ++l) {
    const __bf16* hiL = whiB + (size_t)l * LW;
    const __bf16* loL = wloB + (size_t)l * LW;
    dim3 gDD(D_ / 64, NTOT / 128);
    gemm_mfma<0><<<gDD, 256, 0, stream>>>(be, hiL + 0, loL + 0, bq + l * D_, q_, NTOT, D_, D_);
    gemm_mfma<0><<<gDD, 256, 0, stream>>>(be, hiL + 16384, loL + 16384, bk + l * D_, k_, NTOT, D_, D_);
    gemm_mfma<0><<<gDD, 256, 0, stream>>>(be, hiL + 32768, loL + 32768, bv + l * D_, v_, NTOT, D_, D_);
    attn_kernel<<<B_ * NA * H_ * 2, 256, 0, stream>>>(q_, k_, v_, ct);
    gemm_mfma<0><<<gDD, 256, 0, stream>>>(ct, hiL + 49152, loL + 49152, bo + l * D_, q_, NTOT, D_, D_);
    add_ln_kernel<<<NTOT, 128, 0, stream>>>(be, q_, ln1g + l * D_, ln1b + l * D_, k_);
    for (int c = 0; c < 2; ++c) {
      const int r0 = c * (NTOT / 2);
      gemm_mfma<1><<<dim3(DFF / 64, (NTOT / 2) / 128), 256, 0, stream>>>(
          k_ + (size_t)r0 * D_, hiL + 65536, loL + 65536, b1 + l * DFF, v_,
          NTOT / 2, DFF, D_);
      gemm_mfma<0><<<dim3(D_ / 64, (NTOT / 2) / 128), 256, 0, stream>>>(
          v_, hiL + 131072, loL + 131072, b2 + l * D_, be + (size_t)r0 * D_,
          NTOT / 2, D_, DFF);
    }
    add_ln_kernel<<<NTOT, 128, 0, stream>>>(k_, be, ln2g + l * D_, ln2b + l * D_, be);
  }

  sdot_kernel<<<NTOT / 4, 256, 0, stream>>>(be, bx, bs_);
  hipMemsetAsync(bg_, 0, (size_t)B_ * NN * sizeof(float), stream);
  scatter_kernel<<<(B_ * E_) / 256, 256, 0, stream>>>(bs_, eidx, ew, bg_);
  stats_kernel<<<1, 1024, 0, stream>>>(bg_, bst);
  final_kernel<<<(NTOT * D_) / 256, 256, 0, stream>>>(bg_, bst, bng, bnb, lgw, lgb, out);
}

// Round 6
// 852.092 us; speedup vs baseline: 2.1812x; 1.2694x over previous
//
#include <hip/hip_runtime.h>
#include <hip/hip_bf16.h>
#include <math.h>

#define EPS_ 1e-5f
constexpr int B_ = 4, NA = 64, T_ = 128, D_ = 128, H_ = 8, L_ = 3, DFF = 512, E_ = 65536;
constexpr int DH = D_ / H_;        // 16
constexpr int NN = T_ * NA;        // 8192
constexpr int NTOT = B_ * NA * T_; // 32768

typedef __bf16 bf16x8 __attribute__((ext_vector_type(8)));
typedef float f32x4 __attribute__((ext_vector_type(4)));

// ---------------- embed: x = hist@W + b ; e = x + posenc ----------------
__global__ __launch_bounds__(256) void embed_kernel(
    const float* __restrict__ hist, const float* __restrict__ w,
    const float* __restrict__ b, float* __restrict__ x, float* __restrict__ e) {
  int idx = blockIdx.x * 256 + threadIdx.x;
  if (idx >= NTOT * D_) return;
  int d = idx & (D_ - 1);
  int r = idx >> 7;
  int t = r & (T_ - 1);
  const float* hp = hist + (size_t)r * 3;
  float acc = b[d];
  acc += hp[0] * w[0 * D_ + d];
  acc += hp[1] * w[1 * D_ + d];
  acc += hp[2] * w[2 * D_ + d];
  x[idx] = acc;
  int p = d >> 1;
  float ang = (float)t * expf(-logf(10000.f) * (2.f * (float)p) / (float)D_);
  float pe = (d & 1) ? cosf(ang) : sinf(ang);
  e[idx] = acc + pe;
}

// ---------------- weight split+transpose: W[K][N] fp32 -> Wt hi/lo [N][K] bf16 ----------------
__global__ __launch_bounds__(256) void convert_weights(
    const float* __restrict__ wq, const float* __restrict__ wk,
    const float* __restrict__ wv, const float* __restrict__ wo,
    const float* __restrict__ w1, const float* __restrict__ w2,
    __bf16* __restrict__ hi, __bf16* __restrict__ lo) {
  const int LW = 196608;
  int idx = blockIdx.x * 256 + threadIdx.x;
  if (idx >= L_ * LW) return;
  int l = idx / LW;
  int rem = idx - l * LW;
  float src;
  int dst;
  if (rem < 65536) {
    int which = rem >> 14;
    int r2 = rem & 16383;
    int n = r2 >> 7, k = r2 & 127;
    const float* W = (which == 0) ? wq : (which == 1) ? wk : (which == 2) ? wv : wo;
    src = W[(size_t)l * 16384 + k * 128 + n];
    dst = l * LW + which * 16384 + n * 128 + k;
  } else if (rem < 131072) {
    int r2 = rem - 65536;
    int n = r2 >> 7, k = r2 & 127;
    src = w1[(size_t)l * 65536 + k * 512 + n];
    dst = l * LW + 65536 + n * 128 + k;
  } else {
    int r2 = rem - 131072;
    int n = r2 >> 9, k = r2 & 511;
    src = w2[(size_t)l * 65536 + k * 128 + n];
    dst = l * LW + 131072 + n * 512 + k;
  }
  __bf16 h = (__bf16)src;
  hi[dst] = h;
  lo[dst] = (__bf16)(src - (float)h);
}

// ---------------- MFMA GEMM: C = A[M,K](fp32) @ Wt^T + bias (hi/lo, fp32-grade) ----------------
template <int RELU>
__global__ __launch_bounds__(256) void gemm_mfma(
    const float* __restrict__ A, const __bf16* __restrict__ Whi,
    const __bf16* __restrict__ Wlo, const float* __restrict__ bias,
    float* __restrict__ C, int M, int N, int K) {
  const int wave = threadIdx.x >> 6;
  const int lane = threadIdx.x & 63;
  const int m16 = lane & 15;
  const int quad = lane >> 4;
  const int row0 = blockIdx.y * 128 + wave * 32;
  const int col0 = blockIdx.x * 64;

  f32x4 acc[2][4] = {};
  for (int k0 = 0; k0 < K; k0 += 32) {
    bf16x8 ahi[2], alo[2];
#pragma unroll
    for (int mf = 0; mf < 2; ++mf) {
      const float* ap = A + (size_t)(row0 + mf * 16 + m16) * K + k0 + quad * 8;
      float4 x0 = *(const float4*)ap;
      float4 x1 = *(const float4*)(ap + 4);
      float xv[8] = {x0.x, x0.y, x0.z, x0.w, x1.x, x1.y, x1.z, x1.w};
#pragma unroll
      for (int j = 0; j < 8; ++j) {
        __bf16 h = (__bf16)xv[j];
        ahi[mf][j] = h;
        alo[mf][j] = (__bf16)(xv[j] - (float)h);
      }
    }
    bf16x8 bhi[4], blo[4];
#pragma unroll
    for (int nf = 0; nf < 4; ++nf) {
      size_t off = (size_t)(col0 + nf * 16 + m16) * K + k0 + quad * 8;
      bhi[nf] = *(const bf16x8*)(Whi + off);
      blo[nf] = *(const bf16x8*)(Wlo + off);
    }
#pragma unroll
    for (int mf = 0; mf < 2; ++mf)
#pragma unroll
      for (int nf = 0; nf < 4; ++nf) {
        acc[mf][nf] = __builtin_amdgcn_mfma_f32_16x16x32_bf16(
            ahi[mf], bhi[nf], acc[mf][nf], 0, 0, 0);
        acc[mf][nf] = __builtin_amdgcn_mfma_f32_16x16x32_bf16(
            ahi[mf], blo[nf], acc[mf][nf], 0, 0, 0);
        acc[mf][nf] = __builtin_amdgcn_mfma_f32_16x16x32_bf16(
            alo[mf], bhi[nf], acc[mf][nf], 0, 0, 0);
      }
  }
#pragma unroll
  for (int mf = 0; mf < 2; ++mf)
#pragma unroll
    for (int nf = 0; nf < 4; ++nf) {
      int c = col0 + nf * 16 + m16;
      float bj = bias[c];
#pragma unroll
      for (int reg = 0; reg < 4; ++reg) {
        int r = row0 + mf * 16 + quad * 4 + reg;
        float v = acc[mf][nf][reg] + bj;
        if (RELU) v = fmaxf(v, 0.f);
        C[(size_t)r * N + c] = v;
      }
    }
}

// ---------------- MFMA attention: one block per (b,n,h); 4 waves x 32 q-rows ----------------
// S=Q.K^T via 16x16x32 bf16 mfma (K=16 zero-padded, Q/K hi-lo split -> fp32-grade scores);
// softmax fully in registers (in-lane over 8 col-tiles + shfl_xor within quad);
// P(bf16) -> LDS (row stride 272B: 2-way bank alias = free) -> A-frag; O = P.(Vhi+Vlo).
__global__ __launch_bounds__(256) void attn_mfma(
    const float* __restrict__ q, const float* __restrict__ k,
    const float* __restrict__ v, float* __restrict__ o) {
  const int h = blockIdx.x & (H_ - 1);
  const int bn = blockIdx.x >> 3;
  const int wave = threadIdx.x >> 6;
  const int lane = threadIdx.x & 63;
  const int m16 = lane & 15;
  const int quad = lane >> 4;
  const int row0 = wave * 32;
  const float* Qb = q + (size_t)bn * T_ * D_ + h * DH;
  const float* Kb = k + (size_t)bn * T_ * D_ + h * DH;
  const float* Vb = v + (size_t)bn * T_ * D_ + h * DH;

  __shared__ __bf16 Plds[4][32][136]; // 34816 B; stride 272 B

  // Q A-frags (hi/lo); k = quad*8+j covers 0..31, head has 16 -> quad>=2 is zero pad
  bf16x8 qhi[2], qlo[2];
#pragma unroll
  for (int mf = 0; mf < 2; ++mf) {
    if (quad < 2) {
      const float* ap = Qb + (size_t)(row0 + mf * 16 + m16) * D_ + quad * 8;
      float4 x0 = *(const float4*)ap;
      float4 x1 = *(const float4*)(ap + 4);
      float xv[8] = {x0.x, x0.y, x0.z, x0.w, x1.x, x1.y, x1.z, x1.w};
#pragma unroll
      for (int j = 0; j < 8; ++j) {
        __bf16 hh = (__bf16)xv[j];
        qhi[mf][j] = hh;
        qlo[mf][j] = (__bf16)(xv[j] - (float)hh);
      }
    } else {
#pragma unroll
      for (int j = 0; j < 8; ++j) { qhi[mf][j] = (__bf16)0.f; qlo[mf][j] = (__bf16)0.f; }
    }
  }

  f32x4 acc[2][8] = {};
#pragma unroll
  for (int nf = 0; nf < 8; ++nf) {
    bf16x8 khi, klo;
    if (quad < 2) {
      const float* kp = Kb + (size_t)(nf * 16 + m16) * D_ + quad * 8;
      float4 x0 = *(const float4*)kp;
      float4 x1 = *(const float4*)(kp + 4);
      float xv[8] = {x0.x, x0.y, x0.z, x0.w, x1.x, x1.y, x1.z, x1.w};
#pragma unroll
      for (int j = 0; j < 8; ++j) {
        __bf16 hh = (__bf16)xv[j];
        khi[j] = hh;
        klo[j] = (__bf16)(xv[j] - (float)hh);
      }
    } else {
#pragma unroll
      for (int j = 0; j < 8; ++j) { khi[j] = (__bf16)0.f; klo[j] = (__bf16)0.f; }
    }
#pragma unroll
    for (int mf = 0; mf < 2; ++mf) {
      acc[mf][nf] = __builtin_amdgcn_mfma_f32_16x16x32_bf16(qhi[mf], khi, acc[mf][nf], 0, 0, 0);
      acc[mf][nf] = __builtin_amdgcn_mfma_f32_16x16x32_bf16(qhi[mf], klo, acc[mf][nf], 0, 0, 0);
      acc[mf][nf] = __builtin_amdgcn_mfma_f32_16x16x32_bf16(qlo[mf], khi, acc[mf][nf], 0, 0, 0);
    }
  }

  // softmax: lane holds rows quad*4+reg (+mf*16), cols m16+nf*16
  const float scale = 0.25f;
#pragma unroll
  for (int mf = 0; mf < 2; ++mf)
#pragma unroll
    for (int reg = 0; reg < 4; ++reg) {
      float mx = -1e30f;
#pragma unroll
      for (int nf = 0; nf < 8; ++nf) mx = fmaxf(mx, acc[mf][nf][reg]);
#pragma unroll
      for (int off = 1; off < 16; off <<= 1) mx = fmaxf(mx, __shfl_xor(mx, off, 64));
      float sum = 0.f;
#pragma unroll
      for (int nf = 0; nf < 8; ++nf) {
        float e = __expf((acc[mf][nf][reg] - mx) * scale);
        acc[mf][nf][reg] = e;
        sum += e;
      }
#pragma unroll
      for (int off = 1; off < 16; off <<= 1) sum += __shfl_xor(sum, off, 64);
      float inv = 1.f / sum;
#pragma unroll
      for (int nf = 0; nf < 8; ++nf) acc[mf][nf][reg] *= inv;
    }

  // P -> LDS (C-layout -> A-layout transform)
#pragma unroll
  for (int mf = 0; mf < 2; ++mf)
#pragma unroll
    for (int nf = 0; nf < 8; ++nf)
#pragma unroll
      for (int reg = 0; reg < 4; ++reg)
        Plds[wave][mf * 16 + quad * 4 + reg][nf * 16 + m16] = (__bf16)acc[mf][nf][reg];

  // O = P.V  (P bf16 from LDS, V hi/lo)
  f32x4 oacc[2] = {};
#pragma unroll
  for (int kc = 0; kc < 4; ++kc) {
    bf16x8 pa0 = *(const bf16x8*)&Plds[wave][m16][kc * 32 + quad * 8];
    bf16x8 pa1 = *(const bf16x8*)&Plds[wave][16 + m16][kc * 32 + quad * 8];
    bf16x8 vhi, vlo;
#pragma unroll
    for (int j = 0; j < 8; ++j) {
      float x = Vb[(size_t)(kc * 32 + quad * 8 + j) * D_ + m16];
      __bf16 hh = (__bf16)x;
      vhi[j] = hh;
      vlo[j] = (__bf16)(x - (float)hh);
    }
    oacc[0] = __builtin_amdgcn_mfma_f32_16x16x32_bf16(pa0, vhi, oacc[0], 0, 0, 0);
    oacc[0] = __builtin_amdgcn_mfma_f32_16x16x32_bf16(pa0, vlo, oacc[0], 0, 0, 0);
    oacc[1] = __builtin_amdgcn_mfma_f32_16x16x32_bf16(pa1, vhi, oacc[1], 0, 0, 0);
    oacc[1] = __builtin_amdgcn_mfma_f32_16x16x32_bf16(pa1, vlo, oacc[1], 0, 0, 0);
  }

  float* Ob = o + (size_t)bn * T_ * D_ + h * DH;
#pragma unroll
  for (int mf = 0; mf < 2; ++mf)
#pragma unroll
    for (int reg = 0; reg < 4; ++reg) {
      int r = row0 + mf * 16 + quad * 4 + reg;
      Ob[(size_t)r * D_ + m16] = oacc[mf][reg];
    }
}

// ---------------- residual add + LayerNorm ----------------
__global__ __launch_bounds__(128) void add_ln_kernel(
    const float* __restrict__ a, const float* __restrict__ b,
    const float* __restrict__ gam, const float* __restrict__ bet,
    float* __restrict__ out) {
  int r = blockIdx.x;
  int d = threadIdx.x;
  float val = a[(size_t)r * D_ + d] + b[(size_t)r * D_ + d];
  __shared__ float red[4];
  float s = val;
#pragma unroll
  for (int off = 32; off; off >>= 1) s += __shfl_down(s, off, 64);
  if ((d & 63) == 0) red[d >> 6] = s;
  __syncthreads();
  float mean = (red[0] + red[1]) * (1.f / (float)D_);
  float dv = val - mean;
  float q = dv * dv;
#pragma unroll
  for (int off = 32; off; off >>= 1) q += __shfl_down(q, off, 64);
  if ((d & 63) == 0) red[2 + (d >> 6)] = q;
  __syncthreads();
  float var = (red[2] + red[3]) * (1.f / (float)D_);
  out[(size_t)r * D_ + d] = dv * rsqrtf(var + EPS_) * gam[d] + bet[d];
}

// ---------------- gating dot ----------------
__global__ __launch_bounds__(256) void sdot_kernel(
    const float* __restrict__ e, const float* __restrict__ x, float* __restrict__ s) {
  int r = blockIdx.x * 4 + (threadIdx.x >> 6);
  int lane = threadIdx.x & 63;
  const float* ep = e + (size_t)r * D_;
  const float* xp = x + (size_t)r * D_;
  float acc = ep[lane] * xp[lane] + ep[lane + 64] * xp[lane + 64];
#pragma unroll
  for (int off = 32; off; off >>= 1) acc += __shfl_down(acc, off, 64);
  if (lane == 0) {
    int t = r & (T_ - 1);
    int bn = r >> 7;
    int n = bn & (NA - 1);
    int b = bn >> 6;
    s[(size_t)b * NN + t * NA + n] = acc;
  }
}

// ---------------- edge scatter ----------------
__global__ __launch_bounds__(256) void scatter_kernel(
    const float* __restrict__ s, const int* __restrict__ ei,
    const float* __restrict__ ew, float* __restrict__ g) {
  int idx = blockIdx.x * 256 + threadIdx.x;
  if (idx >= B_ * E_) return;
  int b = idx >> 16;
  int e = idx & (E_ - 1);
  int src = ei[(size_t)b * 2 * E_ + e];
  int dst = ei[(size_t)b * 2 * E_ + E_ + e];
  float w = ew[(size_t)b * E_ + e];
  atomicAdd(&g[(size_t)b * NN + dst], w * s[(size_t)b * NN + src]);
}

// ---------------- partial sums for global mean/var (atomic into st[0],st[1]) ----------------
__global__ __launch_bounds__(256) void stats_partial(
    const float* __restrict__ g, float* __restrict__ st) {
  int i = blockIdx.x * 256 + threadIdx.x;
  float v = g[i];
  float sum = v, sq = v * v;
#pragma unroll
  for (int off = 32; off; off >>= 1) {
    sum += __shfl_down(sum, off, 64);
    sq += __shfl_down(sq, off, 64);
  }
  __shared__ float s1[4], s2[4];
  int w = threadIdx.x >> 6;
  if ((threadIdx.x & 63) == 0) { s1[w] = sum; s2[w] = sq; }
  __syncthreads();
  if (threadIdx.x == 0) {
    atomicAdd(&st[0], s1[0] + s1[1] + s1[2] + s1[3]);
    atomicAdd(&st[1], s2[0] + s2[1] + s2[2] + s2[3]);
  }
}

// ---------------- final (fp32 out); computes mean/var from raw sums ----------------
__global__ __launch_bounds__(256) void final_kernel(
    const float* __restrict__ g, const float* __restrict__ st,
    const float* __restrict__ bng, const float* __restrict__ bnb,
    const float* __restrict__ lw, const float* __restrict__ lb,
    float* __restrict__ out) {
  int idx = blockIdx.x * 256 + threadIdx.x;
  if (idx >= NTOT * D_) return;
  int d = idx & (D_ - 1);
  int r = idx >> 7;
  int t = r & (T_ - 1);
  int bn = r >> 7;
  int n = bn & (NA - 1);
  int b = bn >> 6;
  const float invn = 1.f / (float)(B_ * NN);
  float m = st[0] * invn;
  float var = st[1] * invn - m * m;
  float rs = rsqrtf(var + EPS_);
  float gv = g[(size_t)b * NN + t * NA + n];
  float val = (gv - m) * rs * bng[0] + bnb[0];
  out[idx] = val * lw[d] + lb[d];
}

extern "C" void kernel_launch(void* const* d_in, const int* in_sizes, int n_in,
                              void* d_out, int out_size, void* d_ws, size_t ws_size,
                              hipStream_t stream) {
  const float* hist = (const float*)d_in[0];
  const int* eidx = (const int*)d_in[1];
  const float* ew = (const float*)d_in[2];
  const float* hw = (const float*)d_in[3];
  const float* hb = (const float*)d_in[4];
  const float* wq = (const float*)d_in[5];
  const float* bq = (const float*)d_in[6];
  const float* wk = (const float*)d_in[7];
  const float* bk = (const float*)d_in[8];
  const float* wv = (const float*)d_in[9];
  const float* bv = (const float*)d_in[10];
  const float* wo = (const float*)d_in[11];
  const float* bo = (const float*)d_in[12];
  const float* ln1g = (const float*)d_in[13];
  const float* ln1b = (const float*)d_in[14];
  const float* w1 = (const float*)d_in[15];
  const float* b1 = (const float*)d_in[16];
  const float* w2 = (const float*)d_in[17];
  const float* b2 = (const float*)d_in[18];
  const float* ln2g = (const float*)d_in[19];
  const float* ln2b = (const float*)d_in[20];
  const float* bng = (const float*)d_in[21];
  const float* bnb = (const float*)d_in[22];
  const float* lgw = (const float*)d_in[23];
  const float* lgb = (const float*)d_in[24];
  float* out = (float*)d_out;

  float* ws = (float*)d_ws;
  const size_t NE = (size_t)NTOT * D_;
  float* bx = ws + 0 * NE;
  float* be = ws + 1 * NE;
  float* q_ = ws + 2 * NE;
  float* k_ = ws + 3 * NE; // -> h1
  float* v_ = ws + 4 * NE;
  float* ct = ws + 5 * NE; // attn ctx; {v_, ct} doubles as FF-mid chunk
  float* bs_ = ws + 6 * NE;
  float* bg_ = bs_ + NTOT;
  float* bst = bg_ + NTOT; // st[0]=sum, st[1]=sumsq
  const int LW = 196608;
  __bf16* whiB = (__bf16*)(bst + 2);
  __bf16* wloB = whiB + (size_t)L_ * LW;

  convert_weights<<<(L_ * LW + 255) / 256, 256, 0, stream>>>(
      wq, wk, wv, wo, w1, w2, whiB, wloB);
  embed_kernel<<<(NTOT * D_) / 256, 256, 0, stream>>>(hist, hw, hb, bx, be);

  for (int l = 0; l < L_; ++l) {
    const __bf16* hiL = whiB + (size_t)l * LW;
    const __bf16* loL = wloB + (size_t)l * LW;
    dim3 gDD(D_ / 64, NTOT / 128);
    gemm_mfma<0><<<gDD, 256, 0, stream>>>(be, hiL + 0, loL + 0, bq + l * D_, q_, NTOT, D_, D_);
    gemm_mfma<0><<<gDD, 256, 0, stream>>>(be, hiL + 16384, loL + 16384, bk + l * D_, k_, NTOT, D_, D_);
    gemm_mfma<0><<<gDD, 256, 0, stream>>>(be, hiL + 32768, loL + 32768, bv + l * D_, v_, NTOT, D_, D_);
    attn_mfma<<<B_ * NA * H_, 256, 0, stream>>>(q_, k_, v_, ct);
    gemm_mfma<0><<<gDD, 256, 0, stream>>>(ct, hiL + 49152, loL + 49152, bo + l * D_, q_, NTOT, D_, D_);
    add_ln_kernel<<<NTOT, 128, 0, stream>>>(be, q_, ln1g + l * D_, ln1b + l * D_, k_);
    for (int c = 0; c < 2; ++c) {
      const int r0 = c * (NTOT / 2);
      gemm_mfma<1><<<dim3(DFF / 64, (NTOT / 2) / 128), 256, 0, stream>>>(
          k_ + (size_t)r0 * D_, hiL + 65536, loL + 65536, b1 + l * DFF, v_,
          NTOT / 2, DFF, D_);
      gemm_mfma<0><<<dim3(D_ / 64, (NTOT / 2) / 128), 256, 0, stream>>>(
          v_, hiL + 131072, loL + 131072, b2 + l * D_, be + (size_t)r0 * D_,
          NTOT / 2, D_, DFF);
    }
    add_ln_kernel<<<NTOT, 128, 0, stream>>>(k_, be, ln2g + l * D_, ln2b + l * D_, be);
  }

  sdot_kernel<<<NTOT / 4, 256, 0, stream>>>(be, bx, bs_);
  hipMemsetAsync(bg_, 0, ((size_t)B_ * NN + 2) * sizeof(float), stream);
  scatter_kernel<<<(B_ * E_) / 256, 256, 0, stream>>>(bs_, eidx, ew, bg_);
  stats_partial<<<(B_ * NN) / 256, 256, 0, stream>>>(bg_, bst);
  final_kernel<<<(NTOT * D_) / 256, 256, 0, stream>>>(bg_, bst, bng, bnb, lgw, lgb, out);
}

// Round 7
// 722.732 us; speedup vs baseline: 2.5716x; 1.1790x over previous
//
#include <hip/hip_runtime.h>
#include <hip/hip_bf16.h>
#include <math.h>

#define EPS_ 1e-5f
constexpr int B_ = 4, NA = 64, T_ = 128, D_ = 128, H_ = 8, L_ = 3, DFF = 512, E_ = 65536;
constexpr int DH = D_ / H_;        // 16
constexpr int NN = T_ * NA;        // 8192
constexpr int NTOT = B_ * NA * T_; // 32768
constexpr int QLD = 384;           // packed QKV row stride

typedef __bf16 bf16x8 __attribute__((ext_vector_type(8)));
typedef float f32x4 __attribute__((ext_vector_type(4)));

// ---------------- embed: x = hist@W + b ; e = x + posenc ----------------
__global__ __launch_bounds__(256) void embed_kernel(
    const float* __restrict__ hist, const float* __restrict__ w,
    const float* __restrict__ b, float* __restrict__ x, float* __restrict__ e) {
  int idx = blockIdx.x * 256 + threadIdx.x;
  if (idx >= NTOT * D_) return;
  int d = idx & (D_ - 1);
  int r = idx >> 7;
  int t = r & (T_ - 1);
  const float* hp = hist + (size_t)r * 3;
  float acc = b[d];
  acc += hp[0] * w[0 * D_ + d];
  acc += hp[1] * w[1 * D_ + d];
  acc += hp[2] * w[2 * D_ + d];
  x[idx] = acc;
  int p = d >> 1;
  float ang = (float)t * expf(-logf(10000.f) * (2.f * (float)p) / (float)D_);
  float pe = (d & 1) ? cosf(ang) : sinf(ang);
  e[idx] = acc + pe;
}

// ---------------- weight split+transpose into [N][K] bf16 hi/lo, QKV packed ----------------
// Per-layer elems: qkv=[384][128]@0, wo=[128][128]@49152, w1=[512][128]@65536,
// w2=[128][512]@131072; LW = 196608.
__global__ __launch_bounds__(256) void convert_weights(
    const float* __restrict__ wq, const float* __restrict__ wk,
    const float* __restrict__ wv, const float* __restrict__ wo,
    const float* __restrict__ w1, const float* __restrict__ w2,
    __bf16* __restrict__ hi, __bf16* __restrict__ lo) {
  const int LW = 196608;
  int idx = blockIdx.x * 256 + threadIdx.x;
  if (idx >= L_ * LW) return;
  int l = idx / LW;
  int rem = idx - l * LW;
  float src;
  int dst;
  if (rem < 49152) {
    int n = rem >> 7, k = rem & 127; // n in [0,384)
    int which = n >> 7, nl = n & 127;
    const float* W = (which == 0) ? wq : (which == 1) ? wk : wv;
    src = W[(size_t)l * 16384 + k * 128 + nl];
    dst = l * LW + n * 128 + k;
  } else if (rem < 65536) {
    int r2 = rem - 49152;
    int n = r2 >> 7, k = r2 & 127;
    src = wo[(size_t)l * 16384 + k * 128 + n];
    dst = l * LW + 49152 + n * 128 + k;
  } else if (rem < 131072) {
    int r2 = rem - 65536;
    int n = r2 >> 7, k = r2 & 127; // n in [0,512)
    src = w1[(size_t)l * 65536 + k * 512 + n];
    dst = l * LW + 65536 + n * 128 + k;
  } else {
    int r2 = rem - 131072;
    int n = r2 >> 9, k = r2 & 511; // n in [0,128), k in [0,512)
    src = w2[(size_t)l * 65536 + k * 128 + n];
    dst = l * LW + 131072 + n * 512 + k;
  }
  __bf16 h = (__bf16)src;
  hi[dst] = h;
  lo[dst] = (__bf16)(src - (float)h);
}

// ---------------- pack QKV biases: pb[l][384] = bq|bk|bv ----------------
__global__ __launch_bounds__(256) void bias_pack(
    const float* __restrict__ bq, const float* __restrict__ bk,
    const float* __restrict__ bv, float* __restrict__ pb) {
  int idx = blockIdx.x * 256 + threadIdx.x;
  if (idx >= L_ * QLD) return;
  int l = idx / QLD, n = idx - l * QLD;
  int which = n >> 7, nl = n & 127;
  const float* src = (which == 0) ? bq : (which == 1) ? bk : bv;
  pb[idx] = src[l * 128 + nl];
}

// ---------------- MFMA GEMM, 128x128 block tile, fused epilogues ----------------
// EPI: 0=bias, 1=bias+relu, 2=bias+resid+LayerNorm (requires N==128, gridDim.x==1;
//      resid row stride 128). fp32-grade via hi/lo split (A in-kernel, W pre-split).
template <int EPI>
__global__ __launch_bounds__(256) void gemm_mfma(
    const float* __restrict__ A, int lda,
    const __bf16* __restrict__ Whi, const __bf16* __restrict__ Wlo,
    const float* __restrict__ bias, const float* __restrict__ resid,
    const float* __restrict__ lng, const float* __restrict__ lnb,
    float* __restrict__ C, int ldc, int M, int N, int K) {
  const int wave = threadIdx.x >> 6;
  const int lane = threadIdx.x & 63;
  const int m16 = lane & 15;
  const int quad = lane >> 4;
  const int wrow = wave >> 1, wcol = wave & 1;
  const int row0 = blockIdx.y * 128 + wrow * 64;
  const int col0 = blockIdx.x * 128 + wcol * 64;

  f32x4 acc[4][4] = {};
  for (int k0 = 0; k0 < K; k0 += 32) {
    bf16x8 ahi[4], alo[4];
#pragma unroll
    for (int mf = 0; mf < 4; ++mf) {
      const float* ap = A + (size_t)(row0 + mf * 16 + m16) * lda + k0 + quad * 8;
      float4 x0 = *(const float4*)ap;
      float4 x1 = *(const float4*)(ap + 4);
      float xv[8] = {x0.x, x0.y, x0.z, x0.w, x1.x, x1.y, x1.z, x1.w};
#pragma unroll
      for (int j = 0; j < 8; ++j) {
        __bf16 h = (__bf16)xv[j];
        ahi[mf][j] = h;
        alo[mf][j] = (__bf16)(xv[j] - (float)h);
      }
    }
    bf16x8 bhi[4], blo[4];
#pragma unroll
    for (int nf = 0; nf < 4; ++nf) {
      size_t off = (size_t)(col0 + nf * 16 + m16) * K + k0 + quad * 8;
      bhi[nf] = *(const bf16x8*)(Whi + off);
      blo[nf] = *(const bf16x8*)(Wlo + off);
    }
#pragma unroll
    for (int mf = 0; mf < 4; ++mf)
#pragma unroll
      for (int nf = 0; nf < 4; ++nf) {
        acc[mf][nf] = __builtin_amdgcn_mfma_f32_16x16x32_bf16(ahi[mf], bhi[nf], acc[mf][nf], 0, 0, 0);
        acc[mf][nf] = __builtin_amdgcn_mfma_f32_16x16x32_bf16(ahi[mf], blo[nf], acc[mf][nf], 0, 0, 0);
        acc[mf][nf] = __builtin_amdgcn_mfma_f32_16x16x32_bf16(alo[mf], bhi[nf], acc[mf][nf], 0, 0, 0);
      }
  }

  if (EPI < 2) {
#pragma unroll
    for (int mf = 0; mf < 4; ++mf)
#pragma unroll
      for (int nf = 0; nf < 4; ++nf) {
        int c = col0 + nf * 16 + m16;
        float bj = bias[c];
#pragma unroll
        for (int reg = 0; reg < 4; ++reg) {
          int r = row0 + mf * 16 + quad * 4 + reg;
          float v = acc[mf][nf][reg] + bj;
          if (EPI == 1) v = fmaxf(v, 0.f);
          C[(size_t)r * ldc + c] = v;
        }
      }
  } else {
    __shared__ float rs[128][2], rq[128][2];
#pragma unroll
    for (int mf = 0; mf < 4; ++mf)
#pragma unroll
      for (int reg = 0; reg < 4; ++reg) {
        int lr = wrow * 64 + mf * 16 + quad * 4 + reg; // local row [0,128)
        int gr = blockIdx.y * 128 + lr;
        float s = 0.f, qq = 0.f;
#pragma unroll
        for (int nf = 0; nf < 4; ++nf) {
          int c = col0 + nf * 16 + m16;
          float v = acc[mf][nf][reg] + bias[c] + resid[(size_t)gr * 128 + c];
          acc[mf][nf][reg] = v;
          s += v;
          qq += v * v;
        }
#pragma unroll
        for (int off = 1; off < 16; off <<= 1) {
          s += __shfl_xor(s, off, 64);
          qq += __shfl_xor(qq, off, 64);
        }
        if (m16 == 0) { rs[lr][wcol] = s; rq[lr][wcol] = qq; }
      }
    __syncthreads();
#pragma unroll
    for (int mf = 0; mf < 4; ++mf)
#pragma unroll
      for (int reg = 0; reg < 4; ++reg) {
        int lr = wrow * 64 + mf * 16 + quad * 4 + reg;
        int gr = blockIdx.y * 128 + lr;
        float mean = (rs[lr][0] + rs[lr][1]) * (1.f / 128.f);
        float var = (rq[lr][0] + rq[lr][1]) * (1.f / 128.f) - mean * mean;
        float rstd = rsqrtf(var + EPS_);
#pragma unroll
        for (int nf = 0; nf < 4; ++nf) {
          int c = col0 + nf * 16 + m16;
          C[(size_t)gr * ldc + c] = (acc[mf][nf][reg] - mean) * rstd * lng[c] + lnb[c];
        }
      }
  }
}

// ---------------- MFMA attention on packed QKV; O overwrites the V slice ----------------
__global__ __launch_bounds__(256) void attn_mfma(float* __restrict__ qkv) {
  const int h = blockIdx.x & (H_ - 1);
  const int bn = blockIdx.x >> 3;
  const int wave = threadIdx.x >> 6;
  const int lane = threadIdx.x & 63;
  const int m16 = lane & 15;
  const int quad = lane >> 4;
  const int row0 = wave * 32;
  const float* Qb = qkv + (size_t)bn * T_ * QLD + h * DH;
  const float* Kb = Qb + 128;
  const float* Vb = Qb + 256;
  float* Ob = (float*)Vb; // in-place over V (all reads complete before barrier)

  __shared__ __bf16 Plds[4][32][136]; // 34816 B; row stride 272 B

  bf16x8 qhi[2], qlo[2];
#pragma unroll
  for (int mf = 0; mf < 2; ++mf) {
    if (quad < 2) {
      const float* ap = Qb + (size_t)(row0 + mf * 16 + m16) * QLD + quad * 8;
      float4 x0 = *(const float4*)ap;
      float4 x1 = *(const float4*)(ap + 4);
      float xv[8] = {x0.x, x0.y, x0.z, x0.w, x1.x, x1.y, x1.z, x1.w};
#pragma unroll
      for (int j = 0; j < 8; ++j) {
        __bf16 hh = (__bf16)xv[j];
        qhi[mf][j] = hh;
        qlo[mf][j] = (__bf16)(xv[j] - (float)hh);
      }
    } else {
#pragma unroll
      for (int j = 0; j < 8; ++j) { qhi[mf][j] = (__bf16)0.f; qlo[mf][j] = (__bf16)0.f; }
    }
  }

  f32x4 acc[2][8] = {};
#pragma unroll
  for (int nf = 0; nf < 8; ++nf) {
    bf16x8 khi, klo;
    if (quad < 2) {
      const float* kp = Kb + (size_t)(nf * 16 + m16) * QLD + quad * 8;
      float4 x0 = *(const float4*)kp;
      float4 x1 = *(const float4*)(kp + 4);
      float xv[8] = {x0.x, x0.y, x0.z, x0.w, x1.x, x1.y, x1.z, x1.w};
#pragma unroll
      for (int j = 0; j < 8; ++j) {
        __bf16 hh = (__bf16)xv[j];
        khi[j] = hh;
        klo[j] = (__bf16)(xv[j] - (float)hh);
      }
    } else {
#pragma unroll
      for (int j = 0; j < 8; ++j) { khi[j] = (__bf16)0.f; klo[j] = (__bf16)0.f; }
    }
#pragma unroll
    for (int mf = 0; mf < 2; ++mf) {
      acc[mf][nf] = __builtin_amdgcn_mfma_f32_16x16x32_bf16(qhi[mf], khi, acc[mf][nf], 0, 0, 0);
      acc[mf][nf] = __builtin_amdgcn_mfma_f32_16x16x32_bf16(qhi[mf], klo, acc[mf][nf], 0, 0, 0);
      acc[mf][nf] = __builtin_amdgcn_mfma_f32_16x16x32_bf16(qlo[mf], khi, acc[mf][nf], 0, 0, 0);
    }
  }

  const float scale = 0.25f;
#pragma unroll
  for (int mf = 0; mf < 2; ++mf)
#pragma unroll
    for (int reg = 0; reg < 4; ++reg) {
      float mx = -1e30f;
#pragma unroll
      for (int nf = 0; nf < 8; ++nf) mx = fmaxf(mx, acc[mf][nf][reg]);
#pragma unroll
      for (int off = 1; off < 16; off <<= 1) mx = fmaxf(mx, __shfl_xor(mx, off, 64));
      float sum = 0.f;
#pragma unroll
      for (int nf = 0; nf < 8; ++nf) {
        float e = __expf((acc[mf][nf][reg] - mx) * scale);
        acc[mf][nf][reg] = e;
        sum += e;
      }
#pragma unroll
      for (int off = 1; off < 16; off <<= 1) sum += __shfl_xor(sum, off, 64);
      float inv = 1.f / sum;
#pragma unroll
      for (int nf = 0; nf < 8; ++nf) acc[mf][nf][reg] *= inv;
    }

#pragma unroll
  for (int mf = 0; mf < 2; ++mf)
#pragma unroll
    for (int nf = 0; nf < 8; ++nf)
#pragma unroll
      for (int reg = 0; reg < 4; ++reg)
        Plds[wave][mf * 16 + quad * 4 + reg][nf * 16 + m16] = (__bf16)acc[mf][nf][reg];

  f32x4 oacc[2] = {};
#pragma unroll
  for (int kc = 0; kc < 4; ++kc) {
    bf16x8 pa0 = *(const bf16x8*)&Plds[wave][m16][kc * 32 + quad * 8];
    bf16x8 pa1 = *(const bf16x8*)&Plds[wave][16 + m16][kc * 32 + quad * 8];
    bf16x8 vhi, vlo;
#pragma unroll
    for (int j = 0; j < 8; ++j) {
      float x = Vb[(size_t)(kc * 32 + quad * 8 + j) * QLD + m16];
      __bf16 hh = (__bf16)x;
      vhi[j] = hh;
      vlo[j] = (__bf16)(x - (float)hh);
    }
    oacc[0] = __builtin_amdgcn_mfma_f32_16x16x32_bf16(pa0, vhi, oacc[0], 0, 0, 0);
    oacc[0] = __builtin_amdgcn_mfma_f32_16x16x32_bf16(pa0, vlo, oacc[0], 0, 0, 0);
    oacc[1] = __builtin_amdgcn_mfma_f32_16x16x32_bf16(pa1, vhi, oacc[1], 0, 0, 0);
    oacc[1] = __builtin_amdgcn_mfma_f32_16x16x32_bf16(pa1, vlo, oacc[1], 0, 0, 0);
  }

  __syncthreads(); // all V reads (every wave reads all 128 rows) before any O write
#pragma unroll
  for (int mf = 0; mf < 2; ++mf)
#pragma unroll
    for (int reg = 0; reg < 4; ++reg) {
      int r = row0 + mf * 16 + quad * 4 + reg;
      Ob[(size_t)r * QLD + m16] = oacc[mf][reg];
    }
}

// ---------------- gating dot ----------------
__global__ __launch_bounds__(256) void sdot_kernel(
    const float* __restrict__ e, const float* __restrict__ x, float* __restrict__ s) {
  int r = blockIdx.x * 4 + (threadIdx.x >> 6);
  int lane = threadIdx.x & 63;
  const float* ep = e + (size_t)r * D_;
  const float* xp = x + (size_t)r * D_;
  float acc = ep[lane] * xp[lane] + ep[lane + 64] * xp[lane + 64];
#pragma unroll
  for (int off = 32; off; off >>= 1) acc += __shfl_down(acc, off, 64);
  if (lane == 0) {
    int t = r & (T_ - 1);
    int bn = r >> 7;
    int n = bn & (NA - 1);
    int b = bn >> 6;
    s[(size_t)b * NN + t * NA + n] = acc;
  }
}

// ---------------- edge scatter ----------------
__global__ __launch_bounds__(256) void scatter_kernel(
    const float* __restrict__ s, const int* __restrict__ ei,
    const float* __restrict__ ew, float* __restrict__ g) {
  int idx = blockIdx.x * 256 + threadIdx.x;
  if (idx >= B_ * E_) return;
  int b = idx >> 16;
  int e = idx & (E_ - 1);
  int src = ei[(size_t)b * 2 * E_ + e];
  int dst = ei[(size_t)b * 2 * E_ + E_ + e];
  float w = ew[(size_t)b * E_ + e];
  atomicAdd(&g[(size_t)b * NN + dst], w * s[(size_t)b * NN + src]);
}

// ---------------- partial sums for global mean/var ----------------
__global__ __launch_bounds__(256) void stats_partial(
    const float* __restrict__ g, float* __restrict__ st) {
  int i = blockIdx.x * 256 + threadIdx.x;
  float v = g[i];
  float sum = v, sq = v * v;
#pragma unroll
  for (int off = 32; off; off >>= 1) {
    sum += __shfl_down(sum, off, 64);
    sq += __shfl_down(sq, off, 64);
  }
  __shared__ float s1[4], s2[4];
  int w = threadIdx.x >> 6;
  if ((threadIdx.x & 63) == 0) { s1[w] = sum; s2[w] = sq; }
  __syncthreads();
  if (threadIdx.x == 0) {
    atomicAdd(&st[0], s1[0] + s1[1] + s1[2] + s1[3]);
    atomicAdd(&st[1], s2[0] + s2[1] + s2[2] + s2[3]);
  }
}

// ---------------- final (fp32 out) ----------------
__global__ __launch_bounds__(256) void final_kernel(
    const float* __restrict__ g, const float* __restrict__ st,
    const float* __restrict__ bng, const float* __restrict__ bnb,
    const float* __restrict__ lw, const float* __restrict__ lb,
    float* __restrict__ out) {
  int idx = blockIdx.x * 256 + threadIdx.x;
  if (idx >= NTOT * D_) return;
  int d = idx & (D_ - 1);
  int r = idx >> 7;
  int t = r & (T_ - 1);
  int bn = r >> 7;
  int n = bn & (NA - 1);
  int b = bn >> 6;
  const float invn = 1.f / (float)(B_ * NN);
  float m = st[0] * invn;
  float var = st[1] * invn - m * m;
  float rs = rsqrtf(var + EPS_);
  float gv = g[(size_t)b * NN + t * NA + n];
  float val = (gv - m) * rs * bng[0] + bnb[0];
  out[idx] = val * lw[d] + lb[d];
}

extern "C" void kernel_launch(void* const* d_in, const int* in_sizes, int n_in,
                              void* d_out, int out_size, void* d_ws, size_t ws_size,
                              hipStream_t stream) {
  const float* hist = (const float*)d_in[0];
  const int* eidx = (const int*)d_in[1];
  const float* ew = (const float*)d_in[2];
  const float* hw = (const float*)d_in[3];
  const float* hb = (const float*)d_in[4];
  const float* wq = (const float*)d_in[5];
  const float* bq = (const float*)d_in[6];
  const float* wk = (const float*)d_in[7];
  const float* bk = (const float*)d_in[8];
  const float* wv = (const float*)d_in[9];
  const float* bv = (const float*)d_in[10];
  const float* wo = (const float*)d_in[11];
  const float* bo = (const float*)d_in[12];
  const float* ln1g = (const float*)d_in[13];
  const float* ln1b = (const float*)d_in[14];
  const float* w1 = (const float*)d_in[15];
  const float* b1 = (const float*)d_in[16];
  const float* w2 = (const float*)d_in[17];
  const float* b2 = (const float*)d_in[18];
  const float* ln2g = (const float*)d_in[19];
  const float* ln2b = (const float*)d_in[20];
  const float* bng = (const float*)d_in[21];
  const float* bnb = (const float*)d_in[22];
  const float* lgw = (const float*)d_in[23];
  const float* lgb = (const float*)d_in[24];
  float* out = (float*)d_out;

  // ---- workspace (~115 MB of ~268 MB) ----
  // bx@0, be@NE, h1@2NE, qkv@3NE (3NE, [row][384]); ffmid@3NE (4NE) aliases
  // qkv after attention+O-proj consume it; bs@7NE, bg, bst, pbias, split weights.
  float* ws = (float*)d_ws;
  const size_t NE = (size_t)NTOT * D_;
  float* bx = ws + 0 * NE;
  float* be = ws + 1 * NE;
  float* h1 = ws + 2 * NE;
  float* qkv = ws + 3 * NE;
  float* ffmid = ws + 3 * NE; // 4NE, overlaps dead qkv
  float* bs_ = ws + 7 * NE;
  float* bg_ = bs_ + NTOT;
  float* bst = bg_ + NTOT;
  float* pbias = bst + 2; // L*384
  const int LW = 196608;
  __bf16* whiB = (__bf16*)(pbias + L_ * QLD);
  __bf16* wloB = whiB + (size_t)L_ * LW;

  convert_weights<<<(L_ * LW + 255) / 256, 256, 0, stream>>>(
      wq, wk, wv, wo, w1, w2, whiB, wloB);
  bias_pack<<<(L_ * QLD + 255) / 256, 256, 0, stream>>>(bq, bk, bv, pbias);
  embed_kernel<<<(NTOT * D_) / 256, 256, 0, stream>>>(hist, hw, hb, bx, be);

  for (int l = 0; l < L_; ++l) {
    const __bf16* hiL = whiB + (size_t)l * LW;
    const __bf16* loL = wloB + (size_t)l * LW;
    // QKV: one N=384 GEMM into packed [row][384]
    gemm_mfma<0><<<dim3(3, NTOT / 128), 256, 0, stream>>>(
        be, 128, hiL, loL, pbias + l * QLD, nullptr, nullptr, nullptr,
        qkv, QLD, NTOT, QLD, 128);
    attn_mfma<<<B_ * NA * H_, 256, 0, stream>>>(qkv);
    // O-proj + residual(be) + LN1 -> h1
    gemm_mfma<2><<<dim3(1, NTOT / 128), 256, 0, stream>>>(
        qkv + 256, QLD, hiL + 49152, loL + 49152, bo + l * D_, be,
        ln1g + l * D_, ln1b + l * D_, h1, 128, NTOT, 128, 128);
    // FF1 (relu) -> ffmid
    gemm_mfma<1><<<dim3(4, NTOT / 128), 256, 0, stream>>>(
        h1, 128, hiL + 65536, loL + 65536, b1 + l * DFF, nullptr, nullptr, nullptr,
        ffmid, 512, NTOT, DFF, 128);
    // FF2 + residual(h1) + LN2 -> be
    gemm_mfma<2><<<dim3(1, NTOT / 128), 256, 0, stream>>>(
        ffmid, 512, hiL + 131072, loL + 131072, b2 + l * D_, h1,
        ln2g + l * D_, ln2b + l * D_, be, 128, NTOT, 128, DFF);
  }

  sdot_kernel<<<NTOT / 4, 256, 0, stream>>>(be, bx, bs_);
  hipMemsetAsync(bg_, 0, ((size_t)B_ * NN + 2) * sizeof(float), stream);
  scatter_kernel<<<(B_ * E_) / 256, 256, 0, stream>>>(bs_, eidx, ew, bg_);
  stats_partial<<<(B_ * NN) / 256, 256, 0, stream>>>(bg_, bst);
  final_kernel<<<(NTOT * D_) / 256, 256, 0, stream>>>(bg_, bst, bng, bnb, lgw, lgb, out);
}